// Round 10
// baseline (1512.563 us; speedup 1.0000x reference)
//
#include <hip/hip_runtime.h>
#include <hip/hip_fp16.h>

// ---------------------------------------------------------------------------
// sglayer: k=4 iterations of SpMM (COO segment-sum) then Linear(128->128).
// CSR build (bucket-native): prep -> phase A bucket partition -> phase B
// per-bucket LDS counting sort by (row, col-phase) -> rptr8 + byte-offset
// cols + fp16 weights.
// SpMM: column-phase-banded persistent kernel: ~1000 co-resident blocks,
// each wave owns 25 rows (fp32 acc in regs), sweeps 8 column phases in
// lockstep so the active gather band (~3.2 MB) stays L2-resident per XCD.
// Linear: MFMA 16x16x32 f16.
// ---------------------------------------------------------------------------

#define F 128
#define CH 2048          // edges staged per block in phase A
#define MAXB 256         // max coarse buckets (N <= 131072)
#define RB_LOG 9         // rows per bucket = 512
#define RB (1 << RB_LOG)
#define CAPB 17408       // bucket region capacity (mean 16384, +8 sigma)
#define PH 8             // column phases
#define KEYS (RB * PH)   // 4096 sort keys per bucket
#define RW 25            // rows per wave in persistent SpMM

typedef _Float16 half8 __attribute__((ext_vector_type(8)));
typedef float f32x4 __attribute__((ext_vector_type(4)));

// ---- prep: zero bcnt (block nwb) + W -> fp16 (blocks 0..nwb-1) -----------
__global__ void prep_kernel(const float* __restrict__ W, __half* __restrict__ Wh,
                            int nw, int* __restrict__ bcnt, int nwb) {
  int blk = blockIdx.x;
  if (blk == nwb) {
    int t = threadIdx.x;
    if (t < MAXB) bcnt[t] = 0;
  } else {
    int i = blk * 256 + threadIdx.x;
    if (i < nw) Wh[i] = __float2half(W[i]);
  }
}

// ---- Phase A: LDS-staged partition into fixed-capacity bucket regions ----
// mid[b*CAPB + k] entry: ((row & 511) << 17) | col , weight fp32 bits
__global__ __launch_bounds__(256) void bucket_scatter(
    const int* __restrict__ erow, const int* __restrict__ ecol,
    const float* __restrict__ ew, int* __restrict__ bcnt,
    int2* __restrict__ mid, int e, int nb) {
  __shared__ int  rowv[CH];                // 8 KB raw rows
  __shared__ int2 cw[CH];                  // 16 KB raw (col, wbits)
  __shared__ int2 stage[CH];               // 16 KB bucket-grouped
  __shared__ unsigned short sbid[CH];      // 4 KB
  __shared__ int cnt[MAXB], lstart[MAXB], gbase[MAXB], cnt2[MAXB];
  __shared__ int ps[256];
  int tid = threadIdx.x;
  int base = blockIdx.x * CH;
  int tot = e - base; if (tot > CH) tot = CH;
  for (int t = tid; t < nb; t += 256) { cnt[t] = 0; cnt2[t] = 0; }
  __syncthreads();
  for (int j = tid; j < tot; j += 256) {
    int i = base + j;
    int r = erow[i];
    rowv[j] = r;
    cw[j] = make_int2(ecol[i], __float_as_int(ew[i]));
    atomicAdd(&cnt[r >> RB_LOG], 1);
  }
  __syncthreads();
  int v = (tid < nb) ? cnt[tid] : 0;
  ps[tid] = v;
  __syncthreads();
  for (int off = 1; off < 256; off <<= 1) {
    int u = (tid >= off) ? ps[tid - off] : 0;
    __syncthreads();
    ps[tid] += u;
    __syncthreads();
  }
  if (tid < nb) lstart[tid] = ps[tid] - v;
  __syncthreads();
  for (int t = tid; t < nb; t += 256)
    if (cnt[t] > 0) gbase[t] = atomicAdd(&bcnt[t], cnt[t]);
  __syncthreads();
  for (int j = tid; j < tot; j += 256) {
    int r = rowv[j];
    int bb = r >> RB_LOG;
    int k = atomicAdd(&cnt2[bb], 1);
    int p = lstart[bb] + k;
    stage[p] = make_int2(((r & (RB - 1)) << 17) | cw[j].x, cw[j].y);
    sbid[p] = (unsigned short)bb;
  }
  __syncthreads();
  for (int j = tid; j < tot; j += 256) {   // coalesced bucket runs
    int bb = sbid[j];
    mid[(size_t)bb * CAPB + gbase[bb] + (j - lstart[bb])] = stage[j];
  }
}

// ---- Phase B: per-bucket counting sort by (row, col-phase) ---------------
// Emits rptr8[(r<<3)+s] segment starts, byte-offset cols, fp16 weights.
__global__ __launch_bounds__(256) void csr_sort(
    const int2* __restrict__ mid, const int* __restrict__ bcnt,
    int* __restrict__ rptr8, int* __restrict__ ecols, __half* __restrict__ ewh,
    int n, int nb, unsigned minv8) {
  __shared__ int cnt[KEYS];                // 16 KB: counts -> offsets/cursor
  __shared__ int psum[256];                // 1 KB
  __shared__ int2 st[CAPB];                // 136 KB
  int b = blockIdx.x, tid = threadIdx.x;
  int r0 = b << RB_LOG;
  int r1 = r0 + RB; if (r1 > n) r1 = n;
  int nr = r1 - r0;
  int cntE = bcnt[b];
  const int2* src = mid + (size_t)b * CAPB;

  // base = sum of bcnt[t < b]
  psum[tid] = (tid < b) ? bcnt[tid] : 0;
  __syncthreads();
  for (int off = 128; off > 0; off >>= 1) {
    if (tid < off) psum[tid] += psum[tid + off];
    __syncthreads();
  }
  int bas = psum[0];
  __syncthreads();

  for (int t = tid; t < KEYS; t += 256) cnt[t] = 0;
  __syncthreads();
  for (int i = tid; i < cntE; i += 256) {
    int2 ed = src[i];
    int rl  = ((unsigned)ed.x) >> 17;
    int col = ed.x & 0x1FFFF;
    unsigned ph = __umulhi((unsigned)col, minv8);
    if (ph > PH - 1) ph = PH - 1;
    atomicAdd(&cnt[(rl << 3) | ph], 1);
  }
  __syncthreads();
  // in-place exclusive scan of cnt[0..4096): 16 per thread
  int v[16]; int sum = 0;
#pragma unroll
  for (int t = 0; t < 16; ++t) { v[t] = cnt[tid * 16 + t]; sum += v[t]; }
  psum[tid] = sum;
  __syncthreads();
  for (int off = 1; off < 256; off <<= 1) {
    int u = (tid >= off) ? psum[tid - off] : 0;
    __syncthreads();
    psum[tid] += u;
    __syncthreads();
  }
  int run = (tid > 0) ? psum[tid - 1] : 0;
#pragma unroll
  for (int t = 0; t < 16; ++t) { cnt[tid * 16 + t] = run; run += v[t]; }
  __syncthreads();
  // write rptr8 before cursor destruction
  for (int t = tid; t < nr * PH; t += 256) rptr8[(r0 << 3) + t] = bas + cnt[t];
  if (b == nb - 1 && tid == 0) rptr8[(size_t)n << 3] = bas + cntE;
  // counting sort into LDS (cnt doubles as cursor); col -> byte offset
  for (int i = tid; i < cntE; i += 256) {
    int2 ed = src[i];
    int rl  = ((unsigned)ed.x) >> 17;
    int col = ed.x & 0x1FFFF;
    unsigned ph = __umulhi((unsigned)col, minv8);
    if (ph > PH - 1) ph = PH - 1;
    int p = atomicAdd(&cnt[(rl << 3) | ph], 1);
    st[p] = make_int2(col << 8, ed.y);
  }
  __syncthreads();
  for (int i = tid; i < cntE; i += 256) {
    int2 ed = st[i];
    ecols[bas + i] = ed.x;
    ewh[bas + i]   = __float2half(__int_as_float(ed.y));
  }
}

// ---- persistent column-phase-banded SpMM ---------------------------------
// grid = ceil(N/(4*RW)) blocks (co-resident); wave owns RW rows, lane owns
// 2 feats. Phase loop keeps all waves gathering from the same ~3.2MB band.
__global__ __launch_bounds__(256, 4) void spmm_persist(
    const int* __restrict__ rptr8, const int* __restrict__ ecols,
    const __half* __restrict__ ewh, const __half* __restrict__ xin,
    __half* __restrict__ xout, int n) {
  int lane = threadIdx.x & 63;
  int g = (blockIdx.x << 2) + (threadIdx.x >> 6);
  int r0 = g * RW;
  const char* xb = (const char*)xin;
  float2 acc[RW];
#pragma unroll
  for (int j = 0; j < RW; ++j) acc[j] = make_float2(0.f, 0.f);

  for (int s = 0; s < PH; ++s) {
#pragma unroll
    for (int j = 0; j < RW; ++j) {
      int r = r0 + j;
      if (r < n) {
        int e0 = rptr8[(r << 3) + s];
        int e1 = rptr8[(r << 3) + s + 1];
        float ax = acc[j].x, ay = acc[j].y;
        int e = e0;
        for (; e + 1 < e1; e += 2) {   // 2 independent gathers in flight
          int c0 = ecols[e], c1 = ecols[e + 1];
          float w0 = __half2float(ewh[e]);
          float w1 = __half2float(ewh[e + 1]);
          union { int i; __half2 h2; } u0, u1;
          u0.i = *(const int*)(xb + (size_t)(unsigned)c0 + (lane << 2));
          u1.i = *(const int*)(xb + (size_t)(unsigned)c1 + (lane << 2));
          float2 f0 = __half22float2(u0.h2);
          float2 f1 = __half22float2(u1.h2);
          ax = fmaf(w0, f0.x, ax); ay = fmaf(w0, f0.y, ay);
          ax = fmaf(w1, f1.x, ax); ay = fmaf(w1, f1.y, ay);
        }
        if (e < e1) {
          int c0 = ecols[e];
          float w0 = __half2float(ewh[e]);
          union { int i; __half2 h2; } u0;
          u0.i = *(const int*)(xb + (size_t)(unsigned)c0 + (lane << 2));
          float2 f0 = __half22float2(u0.h2);
          ax = fmaf(w0, f0.x, ax); ay = fmaf(w0, f0.y, ay);
        }
        acc[j].x = ax; acc[j].y = ay;
      }
    }
  }
#pragma unroll
  for (int j = 0; j < RW; ++j) {
    int r = r0 + j;
    if (r < n)
      *(__half2*)((char*)xout + ((size_t)r << 8) + (lane << 2)) =
          __float22half2_rn(acc[j]);
  }
}

__global__ void f32_to_f16(const float2* __restrict__ in, __half2* __restrict__ out, int n2) {
  int i = blockIdx.x * blockDim.x + threadIdx.x;
  if (i < n2) out[i] = __float22half2_rn(in[i]);
}

// ---- Linear via MFMA 16x16x32 f16: out = X(fp16) @ Wh^T + b --------------
__global__ __launch_bounds__(256) void linear_mfma(
    const __half* __restrict__ xin, const __half* __restrict__ Wh,
    const float* __restrict__ b, float* __restrict__ out, int n) {
  int lane = threadIdx.x & 63;
  int wv   = threadIdx.x >> 6;
  int rbase = blockIdx.x * 64 + wv * 16;
  if (rbase >= n) return;
  int arow = rbase + (lane & 15);
  if (arow >= n) arow = n - 1;               // clamp; padded rows discarded
  int koff = (lane >> 4) * 8;                // 8 consecutive k per lane

  half8 a0 = *(const half8*)(xin + (size_t)arow * F + 0  + koff);
  half8 a1 = *(const half8*)(xin + (size_t)arow * F + 32 + koff);
  half8 a2 = *(const half8*)(xin + (size_t)arow * F + 64 + koff);
  half8 a3 = *(const half8*)(xin + (size_t)arow * F + 96 + koff);

  int drow0 = rbase + (lane >> 4) * 4;       // D: row=(l>>4)*4+m, col=l&15
  int dcol  = lane & 15;
#pragma unroll
  for (int jt = 0; jt < 8; ++jt) {
    const __half* wrow = Wh + (size_t)(jt * 16 + (lane & 15)) * F + koff;
    half8 b0 = *(const half8*)(wrow + 0);
    half8 b1 = *(const half8*)(wrow + 32);
    half8 b2 = *(const half8*)(wrow + 64);
    half8 b3 = *(const half8*)(wrow + 96);
    f32x4 acc = {0.f, 0.f, 0.f, 0.f};
    acc = __builtin_amdgcn_mfma_f32_16x16x32_f16(a0, b0, acc, 0, 0, 0);
    acc = __builtin_amdgcn_mfma_f32_16x16x32_f16(a1, b1, acc, 0, 0, 0);
    acc = __builtin_amdgcn_mfma_f32_16x16x32_f16(a2, b2, acc, 0, 0, 0);
    acc = __builtin_amdgcn_mfma_f32_16x16x32_f16(a3, b3, acc, 0, 0, 0);
    float bias = b[jt * 16 + dcol];
#pragma unroll
    for (int m = 0; m < 4; ++m) {
      int r = drow0 + m;
      if (r < n) out[(size_t)r * F + jt * 16 + dcol] = acc[m] + bias;
    }
  }
}

extern "C" void kernel_launch(void* const* d_in, const int* in_sizes, int n_in,
                              void* d_out, int out_size, void* d_ws, size_t ws_size,
                              hipStream_t stream) {
  const float* x    = (const float*)d_in[0];
  const int*   erow = (const int*)d_in[1];
  const int*   ecol = (const int*)d_in[2];
  const float* ew   = (const float*)d_in[3];
  const float* W    = (const float*)d_in[4];
  const float* b    = (const float*)d_in[5];
  float* out = (float*)d_out;

  const int N = in_sizes[0] / F;
  const int E = in_sizes[1];

  char* ws = (char*)d_ws;
  size_t off = 0;
  int*    ecols = (int*)(ws + off);    off += (size_t)E * 4;
  __half* ewh   = (__half*)(ws + off); off += (size_t)E * 2;
  off = (off + 255) & ~(size_t)255;
  int*   rptr8  = (int*)(ws + off);    off += ((size_t)N * PH + 1) * 4;
  int*   bcnt   = (int*)(ws + off);    off += MAXB * 4;
  off = (off + 255) & ~(size_t)255;
  __half* Wh    = (__half*)(ws + off); off += (size_t)F * F * 2;
  off = (off + 255) & ~(size_t)255;
  // big region (51.2 MB): hosts mid (nb*CAPB int2 <= 27.3 MB) during the CSR
  // build, then the fp16 ping-pong buffers A,B (25.6 MB each). mid is fully
  // consumed by csr_sort before f32_to_f16 writes bufB (stream-serial).
  __half* bufA = (__half*)(ws + off);
  __half* bufB = (__half*)(ws + off + (size_t)N * F * 2);
  int2*   mid  = (int2*)bufA;

  const int BK = 256;
  int nb = (N + RB - 1) >> RB_LOG;     // 512-row buckets (<= MAXB)
  int nwb = (F * F + BK - 1) / BK;     // W-conversion blocks
  // phase selector: ph = floor(col * PH / N) via umulhi
  unsigned minv8 = (unsigned)(((unsigned long long)PH << 32) / (unsigned)N + 1);

  // --- prep (zero bcnt + W->fp16) and bucket-native CSR build
  prep_kernel<<<nwb + 1, BK, 0, stream>>>(W, Wh, F * F, bcnt, nwb);
  bucket_scatter<<<(E + CH - 1) / CH, 256, 0, stream>>>(erow, ecol, ew, bcnt, mid, E, nb);
  csr_sort<<<nb, 256, 0, stream>>>(mid, bcnt, rptr8, ecols, ewh, N, nb, minv8);

  // --- convert x to fp16, then 4 persistent SpMM iterations
  int n2 = N * (F / 2);
  f32_to_f16<<<(n2 + BK - 1) / BK, BK, 0, stream>>>((const float2*)x, (__half2*)bufB, n2);
  int pgrid = (N + 4 * RW - 1) / (4 * RW);   // ~1000 blocks, all co-resident
  spmm_persist<<<pgrid, 256, 0, stream>>>(rptr8, ecols, ewh, bufB, bufA, N);
  spmm_persist<<<pgrid, 256, 0, stream>>>(rptr8, ecols, ewh, bufA, bufB, N);
  spmm_persist<<<pgrid, 256, 0, stream>>>(rptr8, ecols, ewh, bufB, bufA, N);
  spmm_persist<<<pgrid, 256, 0, stream>>>(rptr8, ecols, ewh, bufA, bufB, N);

  // --- Linear: bufB (fp16) @ Wh^T + b -> out (fp32), via MFMA
  linear_mfma<<<(N + 63) / 64, 256, 0, stream>>>(bufB, Wh, b, out, N);
}